// Round 3
// baseline (556.651 us; speedup 1.0000x reference)
//
#include <hip/hip_runtime.h>

// ---------------------------------------------------------------------------
// GIN (2 GINConv layers + linear head) on MI355X.
// Round 3: fuse each MLP chain into a single kernel (intermediates in LDS,
// never touch HBM). Kernel A = conv1 MLP (2 GEMMs), kernel B = conv2 MLP +
// head (3 GEMMs). CSR build and agg kernels unchanged from round 2.
// ---------------------------------------------------------------------------

constexpr int BUCKET_SHIFT = 9;            // 512 nodes per bucket
constexpr int BUCKET_NODES = 1 << BUCKET_SHIFT;
constexpr int CAP = 10240;                 // bucket capacity (mean ~8163)
constexpr int EPB = 4096;                  // edges per bucket_scatter block
constexpr int NBUCK_MAX = 256;

__global__ __launch_bounds__(256) void init_gcur_kernel(int* __restrict__ gcur, int nbuck) {
    int i = threadIdx.x;
    if (i < nbuck) gcur[i] = i * CAP;
}

// ---- Phase A: bin edges by dst bucket with LDS staging, coalesced flush ----
__global__ __launch_bounds__(256) void bucket_scatter_kernel(const int* __restrict__ ei, int E,
                                                             int* __restrict__ gcur,
                                                             int* __restrict__ gsrc,
                                                             int* __restrict__ gdst,
                                                             int nbuck) {
    __shared__ int ssrc[EPB];
    __shared__ int sdst[EPB];
    __shared__ int lcnt[NBUCK_MAX];
    __shared__ int lbase[NBUCK_MAX];
    __shared__ int lcur[NBUCK_MAX];
    __shared__ int gbase[NBUCK_MAX];
    __shared__ int stmp[256];

    const int t = threadIdx.x;
    const int e0 = blockIdx.x * EPB;
    const int ecnt = min(EPB, E - e0);

    for (int i = t; i < NBUCK_MAX; i += 256) lcnt[i] = 0;
    __syncthreads();

    for (int i = t; i < ecnt; i += 256) {
        int d = ei[E + e0 + i];
        atomicAdd(&lcnt[d >> BUCKET_SHIFT], 1);
    }
    __syncthreads();

    int v = lcnt[t];
    stmp[t] = v;
    __syncthreads();
    #pragma unroll
    for (int off = 1; off < 256; off <<= 1) {
        int add = (t >= off) ? stmp[t - off] : 0;
        __syncthreads();
        stmp[t] += add;
        __syncthreads();
    }
    lbase[t] = stmp[t] - v;
    lcur[t] = stmp[t] - v;
    __syncthreads();

    for (int i = t; i < ecnt; i += 256) {
        int s = ei[e0 + i];
        int d = ei[E + e0 + i];
        int p = atomicAdd(&lcur[d >> BUCKET_SHIFT], 1);
        ssrc[p] = s;
        sdst[p] = d;
    }
    __syncthreads();

    if (t < nbuck) {
        int c = lcnt[t];
        gbase[t] = (c > 0) ? atomicAdd(&gcur[t], c) : 0;
    }
    __syncthreads();

    for (int i = t; i < ecnt; i += 256) {
        int d = sdst[i];
        int b = d >> BUCKET_SHIFT;
        int gp = gbase[b] + (i - lbase[b]);
        if (gp < (b + 1) * CAP) {
            gsrc[gp] = ssrc[i];
            gdst[gp] = d;
        }
    }
}

// ---- Phase H: per-node histogram, bucket-local via LDS atomics ----
__global__ __launch_bounds__(256) void bucket_hist_kernel(const int* __restrict__ gdst,
                                                          const int* __restrict__ gcur,
                                                          int* __restrict__ cnt, int N) {
    __shared__ int h[BUCKET_NODES];
    const int t = threadIdx.x;
    const int b = blockIdx.x;
    const int base = b << BUCKET_SHIFT;
    for (int i = t; i < BUCKET_NODES; i += 256) h[i] = 0;
    __syncthreads();
    int cb = min(gcur[b] - b * CAP, CAP);
    const int* dd = gdst + (size_t)b * CAP;
    for (int i = t; i < cb; i += 256) atomicAdd(&h[dd[i] - base], 1);
    __syncthreads();
    for (int i = t; i < BUCKET_NODES && base + i < N; i += 256) cnt[base + i] = h[i];
}

// ---- exclusive scan over N node counts ----
__global__ __launch_bounds__(256) void scan_block_kernel(const int* __restrict__ cnt,
                                                         int* __restrict__ rs,
                                                         int* __restrict__ partials,
                                                         int N) {
    __shared__ int s[256];
    int t = threadIdx.x;
    int i = blockIdx.x * 256 + t;
    int v = (i < N) ? cnt[i] : 0;
    s[t] = v;
    __syncthreads();
    #pragma unroll
    for (int off = 1; off < 256; off <<= 1) {
        int add = (t >= off) ? s[t - off] : 0;
        __syncthreads();
        s[t] += add;
        __syncthreads();
    }
    if (i < N) rs[i] = s[t] - v;
    if (t == 255) partials[blockIdx.x] = s[255];
}

__global__ __launch_bounds__(512) void scan_partials_kernel(int* __restrict__ partials,
                                                            int nb) {
    __shared__ int s[512];
    int t = threadIdx.x;
    int v = (t < nb) ? partials[t] : 0;
    s[t] = v;
    __syncthreads();
    #pragma unroll
    for (int off = 1; off < 512; off <<= 1) {
        int add = (t >= off) ? s[t - off] : 0;
        __syncthreads();
        s[t] += add;
        __syncthreads();
    }
    if (t < nb) partials[t] = s[t] - v;
}

__global__ __launch_bounds__(256) void scan_add_kernel(int* __restrict__ rs,
                                                       const int* __restrict__ partials,
                                                       int N, int E) {
    int i = blockIdx.x * 256 + threadIdx.x;
    if (i < N) rs[i] += partials[blockIdx.x];
    if (i == 0) rs[N] = E;
}

// ---- Phase B: exact CSR fill with LDS cursors ----
__global__ __launch_bounds__(256) void bucket_fill_kernel(const int* __restrict__ gsrc,
                                                          const int* __restrict__ gdst,
                                                          const int* __restrict__ gcur,
                                                          const int* __restrict__ rs,
                                                          int* __restrict__ edge_src, int N) {
    __shared__ int cur[BUCKET_NODES];
    const int t = threadIdx.x;
    const int b = blockIdx.x;
    const int base = b << BUCKET_SHIFT;
    for (int i = t; i < BUCKET_NODES; i += 256) cur[i] = rs[min(base + i, N)];
    __syncthreads();
    int cb = min(gcur[b] - b * CAP, CAP);
    const int* ss = gsrc + (size_t)b * CAP;
    const int* dd = gdst + (size_t)b * CAP;
    for (int i = t; i < cb; i += 256) {
        int d = dd[i];
        int s = ss[i];
        int p = atomicAdd(&cur[d - base], 1);
        edge_src[p] = s;
    }
}

// ---------------- aggregation: Z[i] = H[i] + sum_{e: dst=i} H[src[e]] -------

template <int D>
__global__ __launch_bounds__(256) void agg_kernel(const float* __restrict__ H,
                                                  const int* __restrict__ row_start,
                                                  const int* __restrict__ edge_src,
                                                  float* __restrict__ Z, int N) {
    int wave = threadIdx.x >> 6;
    int lane = threadIdx.x & 63;
    int node = blockIdx.x * 4 + wave;
    if (node >= N) return;
    int beg = row_start[node];
    int end = row_start[node + 1];
    const size_t base = (size_t)node * D;
    float acc0 = H[base + lane];
    float acc1 = 0.f;
    if constexpr (D == 128) acc1 = H[base + 64 + lane];
    int i = beg;
    for (; i + 4 <= end; i += 4) {
        int s0 = edge_src[i + 0];
        int s1 = edge_src[i + 1];
        int s2 = edge_src[i + 2];
        int s3 = edge_src[i + 3];
        float a = H[(size_t)s0 * D + lane] + H[(size_t)s1 * D + lane] +
                  H[(size_t)s2 * D + lane] + H[(size_t)s3 * D + lane];
        acc0 += a;
        if constexpr (D == 128) {
            float b = H[(size_t)s0 * D + 64 + lane] + H[(size_t)s1 * D + 64 + lane] +
                      H[(size_t)s2 * D + 64 + lane] + H[(size_t)s3 * D + 64 + lane];
            acc1 += b;
        }
    }
    for (; i < end; ++i) {
        int s = edge_src[i];
        acc0 += H[(size_t)s * D + lane];
        if constexpr (D == 128) acc1 += H[(size_t)s * D + 64 + lane];
    }
    Z[base + lane] = acc0;
    if constexpr (D == 128) Z[base + 64 + lane] = acc1;
}

// ---------------- fused MLP kernels ----------------------------------------
// Block = 256 threads = 64 output rows. Microtile 8 rows x 4 cols (128-wide
// stages) / 4x4 (64-wide stage). A-fragments are scalar LDS reads at a fixed
// k (<=4 distinct addresses per wave -> broadcast). Intermediates stay in LDS.

// Kernel A: h1 = relu( relu(z1 @ Wa + ba) @ Wb + bb ),  z1: [M,64] -> [M,128]
__global__ __launch_bounds__(256) void fused_mlp_A(const float* __restrict__ z,
                                                   const float* __restrict__ Wa,
                                                   const float* __restrict__ ba,
                                                   const float* __restrict__ Wb,
                                                   const float* __restrict__ bb,
                                                   float* __restrict__ Hout, int M) {
    __shared__ float Bz[64][68];    // input tile (full K=64)
    __shared__ float Bs[64][132];   // intermediate tile (128 wide)
    __shared__ float Ws[16 * 128];  // weight chunk

    const int t = threadIdx.x;
    const int m0 = blockIdx.x * 64;
    const int tx = t & 31;          // 32 col-groups of 4 (128 cols)
    const int ty = t >> 5;          // 8 row-groups of 8
    const int col0 = tx * 4;
    const int row0 = ty * 8;

    // load z tile (64 rows x 64 cols)
    for (int i = t; i < 64 * 16; i += 256) {
        int r = i >> 4, c4 = i & 15;
        int gr = min(m0 + r, M - 1);
        *reinterpret_cast<float4*>(&Bz[r][c4 * 4]) =
            *reinterpret_cast<const float4*>(&z[(size_t)gr * 64 + c4 * 4]);
    }
    const float4 ba4 = *reinterpret_cast<const float4*>(&ba[col0]);
    const float4 bb4 = *reinterpret_cast<const float4*>(&bb[col0]);

    float accA[8][4] = {};
    __syncthreads();

    // stage 1: [64x64] @ [64x128]
    for (int kc = 0; kc < 64; kc += 16) {
        for (int i = t; i < 16 * 32; i += 256) {
            int r = i >> 5, c4 = i & 31;
            *reinterpret_cast<float4*>(&Ws[r * 128 + c4 * 4]) =
                *reinterpret_cast<const float4*>(&Wa[(size_t)(kc + r) * 128 + c4 * 4]);
        }
        __syncthreads();
        #pragma unroll
        for (int kk = 0; kk < 16; ++kk) {
            float a[8];
            #pragma unroll
            for (int j = 0; j < 8; ++j) a[j] = Bz[row0 + j][kc + kk];
            const float4 w = *reinterpret_cast<const float4*>(&Ws[kk * 128 + col0]);
            #pragma unroll
            for (int j = 0; j < 8; ++j) {
                accA[j][0] += a[j] * w.x;
                accA[j][1] += a[j] * w.y;
                accA[j][2] += a[j] * w.z;
                accA[j][3] += a[j] * w.w;
            }
        }
        __syncthreads();
    }

    // relu + bias -> Bs
    #pragma unroll
    for (int j = 0; j < 8; ++j) {
        float4 o;
        o.x = fmaxf(accA[j][0] + ba4.x, 0.f);
        o.y = fmaxf(accA[j][1] + ba4.y, 0.f);
        o.z = fmaxf(accA[j][2] + ba4.z, 0.f);
        o.w = fmaxf(accA[j][3] + ba4.w, 0.f);
        *reinterpret_cast<float4*>(&Bs[row0 + j][col0]) = o;
    }

    float accB[8][4] = {};

    // stage 2: [64x128] @ [128x128]
    for (int kc = 0; kc < 128; kc += 16) {
        for (int i = t; i < 16 * 32; i += 256) {
            int r = i >> 5, c4 = i & 31;
            *reinterpret_cast<float4*>(&Ws[r * 128 + c4 * 4]) =
                *reinterpret_cast<const float4*>(&Wb[(size_t)(kc + r) * 128 + c4 * 4]);
        }
        __syncthreads();
        #pragma unroll
        for (int kk = 0; kk < 16; ++kk) {
            float a[8];
            #pragma unroll
            for (int j = 0; j < 8; ++j) a[j] = Bs[row0 + j][kc + kk];
            const float4 w = *reinterpret_cast<const float4*>(&Ws[kk * 128 + col0]);
            #pragma unroll
            for (int j = 0; j < 8; ++j) {
                accB[j][0] += a[j] * w.x;
                accB[j][1] += a[j] * w.y;
                accB[j][2] += a[j] * w.z;
                accB[j][3] += a[j] * w.w;
            }
        }
        __syncthreads();
    }

    // relu + bias -> global
    #pragma unroll
    for (int j = 0; j < 8; ++j) {
        int grow = m0 + row0 + j;
        if (grow < M) {
            float4 o;
            o.x = fmaxf(accB[j][0] + bb4.x, 0.f);
            o.y = fmaxf(accB[j][1] + bb4.y, 0.f);
            o.z = fmaxf(accB[j][2] + bb4.z, 0.f);
            o.w = fmaxf(accB[j][3] + bb4.w, 0.f);
            *reinterpret_cast<float4*>(&Hout[(size_t)grow * 128 + col0]) = o;
        }
    }
}

// Kernel B: out = relu( relu(z2 @ Wa + ba) @ Wb + bb ) @ Wl + bl
//           z2: [M,128] -> [M,64]
__global__ __launch_bounds__(256) void fused_mlp_B(const float* __restrict__ z,
                                                   const float* __restrict__ Wa,
                                                   const float* __restrict__ ba,
                                                   const float* __restrict__ Wb,
                                                   const float* __restrict__ bb,
                                                   const float* __restrict__ Wl,
                                                   const float* __restrict__ bl,
                                                   float* __restrict__ Out, int M) {
    __shared__ float Bz[64][132];   // input tile (K=128); reused for stage-2 out
    __shared__ float Bs[64][132];   // intermediate tile
    __shared__ float Ws[16 * 128];  // weight chunk

    const int t = threadIdx.x;
    const int m0 = blockIdx.x * 64;
    const int tx = t & 31;
    const int ty = t >> 5;
    const int col0 = tx * 4;
    const int row0 = ty * 8;

    // load z tile (64 rows x 128 cols)
    for (int i = t; i < 64 * 32; i += 256) {
        int r = i >> 5, c4 = i & 31;
        int gr = min(m0 + r, M - 1);
        *reinterpret_cast<float4*>(&Bz[r][c4 * 4]) =
            *reinterpret_cast<const float4*>(&z[(size_t)gr * 128 + c4 * 4]);
    }
    const float4 ba4 = *reinterpret_cast<const float4*>(&ba[col0]);
    const float4 bb4 = *reinterpret_cast<const float4*>(&bb[col0]);

    float accA[8][4] = {};
    __syncthreads();

    // stage 1: [64x128] @ [128x128]
    for (int kc = 0; kc < 128; kc += 16) {
        for (int i = t; i < 16 * 32; i += 256) {
            int r = i >> 5, c4 = i & 31;
            *reinterpret_cast<float4*>(&Ws[r * 128 + c4 * 4]) =
                *reinterpret_cast<const float4*>(&Wa[(size_t)(kc + r) * 128 + c4 * 4]);
        }
        __syncthreads();
        #pragma unroll
        for (int kk = 0; kk < 16; ++kk) {
            float a[8];
            #pragma unroll
            for (int j = 0; j < 8; ++j) a[j] = Bz[row0 + j][kc + kk];
            const float4 w = *reinterpret_cast<const float4*>(&Ws[kk * 128 + col0]);
            #pragma unroll
            for (int j = 0; j < 8; ++j) {
                accA[j][0] += a[j] * w.x;
                accA[j][1] += a[j] * w.y;
                accA[j][2] += a[j] * w.z;
                accA[j][3] += a[j] * w.w;
            }
        }
        __syncthreads();
    }

    #pragma unroll
    for (int j = 0; j < 8; ++j) {
        float4 o;
        o.x = fmaxf(accA[j][0] + ba4.x, 0.f);
        o.y = fmaxf(accA[j][1] + ba4.y, 0.f);
        o.z = fmaxf(accA[j][2] + ba4.z, 0.f);
        o.w = fmaxf(accA[j][3] + ba4.w, 0.f);
        *reinterpret_cast<float4*>(&Bs[row0 + j][col0]) = o;
    }

    float accB[8][4] = {};

    // stage 2: [64x128] @ [128x128]  (output -> Bz, reused)
    for (int kc = 0; kc < 128; kc += 16) {
        for (int i = t; i < 16 * 32; i += 256) {
            int r = i >> 5, c4 = i & 31;
            *reinterpret_cast<float4*>(&Ws[r * 128 + c4 * 4]) =
                *reinterpret_cast<const float4*>(&Wb[(size_t)(kc + r) * 128 + c4 * 4]);
        }
        __syncthreads();
        #pragma unroll
        for (int kk = 0; kk < 16; ++kk) {
            float a[8];
            #pragma unroll
            for (int j = 0; j < 8; ++j) a[j] = Bs[row0 + j][kc + kk];
            const float4 w = *reinterpret_cast<const float4*>(&Ws[kk * 128 + col0]);
            #pragma unroll
            for (int j = 0; j < 8; ++j) {
                accB[j][0] += a[j] * w.x;
                accB[j][1] += a[j] * w.y;
                accB[j][2] += a[j] * w.z;
                accB[j][3] += a[j] * w.w;
            }
        }
        __syncthreads();
    }

    // relu + bias -> Bz (stage-3 input); Bz reads finished in stage 1
    #pragma unroll
    for (int j = 0; j < 8; ++j) {
        float4 o;
        o.x = fmaxf(accB[j][0] + bb4.x, 0.f);
        o.y = fmaxf(accB[j][1] + bb4.y, 0.f);
        o.z = fmaxf(accB[j][2] + bb4.z, 0.f);
        o.w = fmaxf(accB[j][3] + bb4.w, 0.f);
        *reinterpret_cast<float4*>(&Bz[row0 + j][col0]) = o;
    }

    // stage 3: [64x128] @ [128x64] — remap threads: 4 rows x 4 cols each
    const int tx3 = t & 15;         // 16 col-groups of 4 (64 cols)
    const int ty3 = t >> 4;         // 16 row-groups of 4
    const int col3 = tx3 * 4;
    const int row3 = ty3 * 4;
    const float4 bl4 = *reinterpret_cast<const float4*>(&bl[col3]);

    float accC[4][4] = {};
    for (int kc = 0; kc < 128; kc += 16) {
        for (int i = t; i < 16 * 16; i += 256) {
            int r = i >> 4, c4 = i & 15;
            *reinterpret_cast<float4*>(&Ws[r * 64 + c4 * 4]) =
                *reinterpret_cast<const float4*>(&Wl[(size_t)(kc + r) * 64 + c4 * 4]);
        }
        __syncthreads();
        #pragma unroll
        for (int kk = 0; kk < 16; ++kk) {
            float a[4];
            #pragma unroll
            for (int j = 0; j < 4; ++j) a[j] = Bz[row3 + j][kc + kk];
            const float4 w = *reinterpret_cast<const float4*>(&Ws[kk * 64 + col3]);
            #pragma unroll
            for (int j = 0; j < 4; ++j) {
                accC[j][0] += a[j] * w.x;
                accC[j][1] += a[j] * w.y;
                accC[j][2] += a[j] * w.z;
                accC[j][3] += a[j] * w.w;
            }
        }
        __syncthreads();
    }

    #pragma unroll
    for (int j = 0; j < 4; ++j) {
        int grow = m0 + row3 + j;
        if (grow < M) {
            float4 o;
            o.x = accC[j][0] + bl4.x;
            o.y = accC[j][1] + bl4.y;
            o.z = accC[j][2] + bl4.z;
            o.w = accC[j][3] + bl4.w;
            *reinterpret_cast<float4*>(&Out[(size_t)grow * 64 + col3]) = o;
        }
    }
}

// ---------------------------------------------------------------------------

extern "C" void kernel_launch(void* const* d_in, const int* in_sizes, int n_in,
                              void* d_out, int out_size, void* d_ws, size_t ws_size,
                              hipStream_t stream) {
    const float* x    = (const float*)d_in[0];
    const int*   ei   = (const int*)d_in[1];
    const float* W1a  = (const float*)d_in[2];
    const float* b1a  = (const float*)d_in[3];
    const float* W1b  = (const float*)d_in[4];
    const float* b1b  = (const float*)d_in[5];
    const float* W2a  = (const float*)d_in[6];
    const float* b2a  = (const float*)d_in[7];
    const float* W2b  = (const float*)d_in[8];
    const float* b2b  = (const float*)d_in[9];
    const float* Wlin = (const float*)d_in[10];
    const float* blin = (const float*)d_in[11];
    float* out = (float*)d_out;

    const int N = in_sizes[0] / 64;   // 100000
    const int E = in_sizes[1] / 2;    // 1600000
    const int NBUCK = (N + BUCKET_NODES - 1) >> BUCKET_SHIFT;  // 196

    // workspace layout
    char* ws = (char*)d_ws;
    const size_t bufBytes = (size_t)N * 128 * sizeof(float);  // 51.2 MB
    float* A  = (float*)(ws + 0);
    float* B  = (float*)(ws + bufBytes);
    float* Cb = (float*)(ws + 2 * bufBytes);
    size_t off = 3 * bufBytes;
    int* row_start = (int*)(ws + off); off += ((size_t)(N + 1) * 4 + 15) & ~(size_t)15;
    int* cnt       = (int*)(ws + off); off += ((size_t)N * 4 + 15) & ~(size_t)15;
    int* partials  = (int*)(ws + off); off += 4096;
    int* gcur      = (int*)(ws + off); off += 4096;
    int* edge_src  = (int*)(ws + off); off += (size_t)E * 4;
    // gsrc/gdst alias the B buffer (only used during CSR build)
    int* gsrc = (int*)B;
    int* gdst = (int*)B + (size_t)NBUCK * CAP;

    const int NB_N = (N + 255) / 256;          // 391
    const int NB_A = (N + 3) / 4;              // 25000 agg blocks
    const int NB_G = (N + 63) / 64;            // 1563 fused-MLP blocks
    const int NB_S = (E + EPB - 1) / EPB;      // 391 scatter blocks

    // 1. CSR build, bucket-binned
    init_gcur_kernel<<<1, 256, 0, stream>>>(gcur, NBUCK);
    bucket_scatter_kernel<<<NB_S, 256, 0, stream>>>(ei, E, gcur, gsrc, gdst, NBUCK);
    bucket_hist_kernel<<<NBUCK, 256, 0, stream>>>(gdst, gcur, cnt, N);
    scan_block_kernel<<<NB_N, 256, 0, stream>>>(cnt, row_start, partials, N);
    scan_partials_kernel<<<1, 512, 0, stream>>>(partials, NB_N);
    scan_add_kernel<<<NB_N, 256, 0, stream>>>(row_start, partials, N, E);
    bucket_fill_kernel<<<NBUCK, 256, 0, stream>>>(gsrc, gdst, gcur, row_start, edge_src, N);

    // 2. conv1: agg + fused MLP
    agg_kernel<64><<<NB_A, 256, 0, stream>>>(x, row_start, edge_src, A, N);
    fused_mlp_A<<<NB_G, 256, 0, stream>>>(A, W1a, b1a, W1b, b1b, Cb, N);   // Cb = h1

    // 3. conv2 + head: agg + fused MLP(+head)
    agg_kernel<128><<<NB_A, 256, 0, stream>>>(Cb, row_start, edge_src, A, N);
    fused_mlp_B<<<NB_G, 256, 0, stream>>>(A, W2a, b2a, W2b, b2b, Wlin, blin, out, N);
}